// Round 4
// baseline (157.730 us; speedup 1.0000x reference)
//
#include <hip/hip_runtime.h>
#include <math.h>

#define NPARTS 8
#define NKP 32768
#define BDIM 64
#define NJ 7
#define NPTS (NPARTS * NKP)        // 262144 points
#define WSTRIDE (NPTS * 3)         // 786432 floats per beta slice
#define NBLK (NPTS / 128)          // 2048 blocks

// d_out flat layout (return-order concatenation)
#define OFF_OBJ    0
#define OFF_BASET  1
#define OFF_REL    17
#define OFF_NANCH  129
#define OFF_NAXIS  150
#define OFF_JLOC   171
#define OFF_JAXIS  192
#define OFF_NKPOUT 213
// total = 213 + 786432 = 786645

// d_ws layout: [0..NBLK) partials (float), [NBLK] counter (uint, memset to 0
// at the start of every call -> no cross-call state).

// ---------------------------------------------------------------------------
// Single fused kernel. 2048 blocks x 256 (8 blocks/CU, fully resident).
//  - wave-0 prologue: quaternion -> base_T; blocks needing a joint compute
//    beta·W_loc / beta·W_axis for ONE joint via 64-lane butterfly reduce,
//    then the axis-angle 3x4 and child_T = rel @ base_T. Blocks 1..7 write
//    the small per-joint outputs; block 0 writes base_T.
//  - main loop: e-split-halves einsum over W_kp (float3 streams), LDS
//    combine, norm_kp store, weighted-distance objective, block reduce.
//  - tail: release-store partial, acq_rel counter increment; LAST block
//    acquire-loads all partials (agent scope, bypasses stale per-XCD L2),
//    fixed-tree reduces, adds beta regularizer, writes out[0].
// ---------------------------------------------------------------------------
__global__ __launch_bounds__(256) void fused_all(
    const float* __restrict__ W_kp, const float* __restrict__ beta,
    const float* __restrict__ pred_kp, const float* __restrict__ wgt,
    const float* __restrict__ quat, const float* __restrict__ base_t,
    const float* __restrict__ jstate, const float* __restrict__ W_loc,
    const float* __restrict__ W_axis, float* __restrict__ out,
    float* __restrict__ partials, unsigned int* __restrict__ counter) {
  __shared__ float sb[BDIM];
  __shared__ float Ts[16];
  __shared__ float part[128 * 3];
  __shared__ float red[4];
  __shared__ int lastflag;

  const int tid = threadIdx.x;
  const int bid = blockIdx.x;
  const int pid = bid >> 8;  // part id (256 blocks per part)

  if (tid < BDIM) sb[tid] = beta[tid];

  if (tid < 64) {
    // --- base transform (all lanes of wave 0, redundantly: cheap) ---
    float q0 = quat[0], q1 = quat[1], q2 = quat[2], q3 = quat[3];
    float qn = sqrtf(q0 * q0 + q1 * q1 + q2 * q2 + q3 * q3);
    float a = q0 / qn, b = q1 / qn, c = q2 / qn, d = q3 / qn;
    float R00 = 1.f - 2.f * c * c - 2.f * d * d, R01 = 2.f * b * c - 2.f * a * d,
          R02 = 2.f * a * c + 2.f * b * d;
    float R10 = 2.f * b * c + 2.f * a * d, R11 = 1.f - 2.f * b * b - 2.f * d * d,
          R12 = 2.f * c * d - 2.f * a * b;
    float R20 = 2.f * b * d - 2.f * a * c, R21 = 2.f * a * b + 2.f * c * d,
          R22 = 1.f - 2.f * b * b - 2.f * c * c;
    float t0 = base_t[0], t1 = base_t[1], t2 = base_t[2];
    float T[16] = {R00, R01, R02, t0, R10, R11, R12, t1,
                   R20, R21, R22, t2, 0.f, 0.f, 0.f, 1.f};

    const bool write_small = (bid >= 1 && bid <= NJ);  // blocks 1..7, all pid==0
    const bool need_joint = (pid > 0) || write_small;

    if (need_joint) {
      const int j = (pid > 0) ? (pid - 1) : (bid - 1);
      // lane e = tid: partial products, butterfly-reduce 6 quantities
      float be = beta[tid];
      float l0 = be * W_loc[tid * 21 + j * 3 + 0];
      float l1 = be * W_loc[tid * 21 + j * 3 + 1];
      float l2 = be * W_loc[tid * 21 + j * 3 + 2];
      float x0 = be * W_axis[tid * 21 + j * 3 + 0];
      float x1 = be * W_axis[tid * 21 + j * 3 + 1];
      float x2 = be * W_axis[tid * 21 + j * 3 + 2];
#pragma unroll
      for (int off = 32; off > 0; off >>= 1) {
        l0 += __shfl_xor(l0, off, 64);
        l1 += __shfl_xor(l1, off, 64);
        l2 += __shfl_xor(l2, off, 64);
        x0 += __shfl_xor(x0, off, 64);
        x1 += __shfl_xor(x1, off, 64);
        x2 += __shfl_xor(x2, off, 64);
      }
      float xn = sqrtf(x0 * x0 + x1 * x1 + x2 * x2);
      x0 /= xn; x1 /= xn; x2 /= xn;
      float aa = R00 * l0 + R01 * l1 + R02 * l2 + t0;
      float bb = R10 * l0 + R11 * l1 + R12 * l2 + t1;
      float cc = R20 * l0 + R21 * l1 + R22 * l2 + t2;
      float u = R00 * x0 + R01 * x1 + R02 * x2;
      float v = R10 * x0 + R11 * x1 + R12 * x2;
      float w = R20 * x0 + R21 * x1 + R22 * x2;
      float th = jstate[j];
      float cth = cosf(-th), sth = sinf(-th), omc = 1.f - cth;
      float rel[12];
      rel[0]  = u * u + (v * v + w * w) * cth;
      rel[1]  = u * v * omc - w * sth;
      rel[2]  = u * w * omc + v * sth;
      rel[3]  = (aa * (v * v + w * w) - u * (bb * v + cc * w)) * omc + (bb * w - cc * v) * sth;
      rel[4]  = u * v * omc + w * sth;
      rel[5]  = v * v + (u * u + w * w) * cth;
      rel[6]  = v * w * omc - u * sth;
      rel[7]  = (bb * (u * u + w * w) - v * (aa * u + cc * w)) * omc + (cc * u - aa * w) * sth;
      rel[8]  = u * w * omc - v * sth;
      rel[9]  = v * w * omc + u * sth;
      rel[10] = w * w + (u * u + v * v) * cth;
      rel[11] = (cc * (u * u + v * v) - w * (aa * u + bb * v)) * omc + (aa * v - bb * u) * sth;
      // child_T rows 0..2 = rel(3x4) @ T(4x4)
      float C[12];
#pragma unroll
      for (int r = 0; r < 3; r++)
#pragma unroll
        for (int cx = 0; cx < 4; cx++)
          C[r * 4 + cx] = rel[r * 4 + 0] * T[0 + cx] + rel[r * 4 + 1] * T[4 + cx] +
                          rel[r * 4 + 2] * T[8 + cx] + rel[r * 4 + 3] * T[12 + cx];
      if (tid == 0) {
        if (pid > 0) {
          for (int i = 0; i < 12; i++) Ts[i] = C[i];
          Ts[12] = 0.f; Ts[13] = 0.f; Ts[14] = 0.f; Ts[15] = 1.f;
        } else {
          for (int i = 0; i < 16; i++) Ts[i] = T[i];
        }
        if (write_small) {
          out[OFF_JLOC + j * 3 + 0] = l0;
          out[OFF_JLOC + j * 3 + 1] = l1;
          out[OFF_JLOC + j * 3 + 2] = l2;
          out[OFF_JAXIS + j * 3 + 0] = x0;
          out[OFF_JAXIS + j * 3 + 1] = x1;
          out[OFF_JAXIS + j * 3 + 2] = x2;
          out[OFF_NANCH + j * 3 + 0] = aa;
          out[OFF_NANCH + j * 3 + 1] = bb;
          out[OFF_NANCH + j * 3 + 2] = cc;
          out[OFF_NAXIS + j * 3 + 0] = u;
          out[OFF_NAXIS + j * 3 + 1] = v;
          out[OFF_NAXIS + j * 3 + 2] = w;
          for (int i = 0; i < 12; i++) out[OFF_REL + j * 16 + i] = rel[i];
          out[OFF_REL + j * 16 + 12] = 0.f;
          out[OFF_REL + j * 16 + 13] = 0.f;
          out[OFF_REL + j * 16 + 14] = 0.f;
          out[OFF_REL + j * 16 + 15] = 1.f;
        }
      }
    } else if (tid == 0) {
      for (int i = 0; i < 16; i++) Ts[i] = T[i];
      if (bid == 0)
        for (int i = 0; i < 16; i++) out[OFF_BASET + i] = T[i];
    }
  }
  __syncthreads();

  // --- main einsum + objective ---
  const int idx = tid & 127;  // point-within-block
  const int h = tid >> 7;     // e-half (wave-uniform)
  const int p = bid * 128 + idx;

  const float* base = W_kp + (size_t)(h * 32) * WSTRIDE + (size_t)p * 3;
  float ax = 0.f, ay = 0.f, az = 0.f;
#pragma unroll 8
  for (int e = 0; e < 32; e++) {
    float3 vv = *(const float3*)(base + (size_t)e * WSTRIDE);
    float be = sb[h * 32 + e];
    ax = fmaf(be, vv.x, ax);
    ay = fmaf(be, vv.y, ay);
    az = fmaf(be, vv.z, az);
  }

  if (h == 1) {
    part[idx * 3 + 0] = ax;
    part[idx * 3 + 1] = ay;
    part[idx * 3 + 2] = az;
  }
  __syncthreads();

  float vsum = 0.f;
  if (h == 0) {
    float x = ax + part[idx * 3 + 0];
    float y = ay + part[idx * 3 + 1];
    float z = az + part[idx * 3 + 2];
    float3 o; o.x = x; o.y = y; o.z = z;
    *(float3*)(out + OFF_NKPOUT + (size_t)p * 3) = o;

    float3 pk = *(const float3*)(pred_kp + (size_t)p * 3);
    float w = wgt[p];
    float dx = Ts[0] * x + Ts[1] * y + Ts[2]  * z + Ts[3]  - pk.x;
    float dy = Ts[4] * x + Ts[5] * y + Ts[6]  * z + Ts[7]  - pk.y;
    float dz = Ts[8] * x + Ts[9] * y + Ts[10] * z + Ts[11] - pk.z;
    vsum = sqrtf(dx * dx + dy * dy + dz * dz) * w;
  }
#pragma unroll
  for (int off = 32; off > 0; off >>= 1) vsum += __shfl_down(vsum, off, 64);
  if ((tid & 63) == 0) red[tid >> 6] = vsum;
  __syncthreads();

  // --- partial publish + last-block final reduce ---
  if (tid == 0) {
    float psum = red[0] + red[1] + red[2] + red[3];
    __hip_atomic_store(&partials[bid], psum, __ATOMIC_RELEASE,
                       __HIP_MEMORY_SCOPE_AGENT);
    unsigned int old = __hip_atomic_fetch_add(counter, 1u, __ATOMIC_ACQ_REL,
                                              __HIP_MEMORY_SCOPE_AGENT);
    lastflag = (old == NBLK - 1) ? 1 : 0;
  }
  __syncthreads();
  if (lastflag) {
    float s = 0.f;
#pragma unroll
    for (int k = 0; k < NBLK / 256; k++)
      s += __hip_atomic_load(&partials[tid + 256 * k], __ATOMIC_ACQUIRE,
                             __HIP_MEMORY_SCOPE_AGENT);
#pragma unroll
    for (int off = 32; off > 0; off >>= 1) s += __shfl_down(s, off, 64);
    if ((tid & 63) == 0) red[tid >> 6] = s;
    __syncthreads();
    if (tid == 0) {
      float reg = 0.f;
      for (int e = 0; e < BDIM; e++) reg += sb[e] * sb[e];
      out[OFF_OBJ] = (red[0] + red[1] + red[2] + red[3]) * (1.f / (float)NPTS) +
                     (reg / (float)BDIM) * 0.001f;
    }
  }
}

extern "C" void kernel_launch(void* const* d_in, const int* in_sizes, int n_in,
                              void* d_out, int out_size, void* d_ws, size_t ws_size,
                              hipStream_t stream) {
  const float* pred_kp = (const float*)d_in[0];
  const float* quat    = (const float*)d_in[1];
  const float* base_t  = (const float*)d_in[2];
  const float* jstate  = (const float*)d_in[3];
  const float* beta    = (const float*)d_in[4];
  const float* wgt     = (const float*)d_in[5];
  const float* W_kp    = (const float*)d_in[6];
  const float* W_loc   = (const float*)d_in[7];
  const float* W_axis  = (const float*)d_in[8];
  float* out = (float*)d_out;
  float* partials = (float*)d_ws;
  unsigned int* counter = (unsigned int*)((char*)d_ws + NBLK * sizeof(float));

  hipMemsetAsync(counter, 0, sizeof(unsigned int), stream);
  fused_all<<<NBLK, 256, 0, stream>>>(W_kp, beta, pred_kp, wgt, quat, base_t,
                                      jstate, W_loc, W_axis, out, partials,
                                      counter);
}

// Round 5
// 38.683 us; speedup vs baseline: 4.0775x; 4.0775x over previous
//
#include <hip/hip_runtime.h>
#include <math.h>

#define NPARTS 8
#define NKP 32768
#define BDIM 64
#define NJ 7
#define NPTS (NPARTS * NKP)        // 262144 points
#define WSTRIDE (NPTS * 3)         // 786432 floats per beta slice
#define NBLK (NPTS / 128)          // 2048 blocks

// d_out flat layout (return-order concatenation)
#define OFF_OBJ    0
#define OFF_BASET  1
#define OFF_REL    17
#define OFF_NANCH  129
#define OFF_NAXIS  150
#define OFF_JLOC   171
#define OFF_JAXIS  192
#define OFF_NKPOUT 213
// total = 213 + 786432 = 786645

// d_ws layout: [0..NBLK) per-block partials (float). Plain stores only —
// visibility to finish_kernel is guaranteed by the kernel boundary.

// ---------------------------------------------------------------------------
// Kernel 1 (fused): prologue pose math + einsum + objective partial.
// 2048 blocks x 256 (8 blocks/CU fully resident).
//  - wave-0 prologue: quaternion -> base_T; blocks needing a joint compute
//    beta·W_loc / beta·W_axis for ONE joint via 64-lane butterfly reduce,
//    then the axis-angle 3x4 and child_T = rel @ base_T. Blocks 1..7 write
//    the small per-joint outputs; block 0 writes base_T.
//  - main loop: e-split-halves einsum over W_kp (float3 streams), LDS
//    combine, norm_kp store, weighted-distance objective, block reduce.
//  - epilogue: ONE plain store of the block partial. NO atomics (round-4
//    lesson: per-block agent-scope acq_rel atomics cost ~200 us in cache
//    maintenance + cross-XCD RMW serialization).
// ---------------------------------------------------------------------------
__global__ __launch_bounds__(256) void fused_all(
    const float* __restrict__ W_kp, const float* __restrict__ beta,
    const float* __restrict__ pred_kp, const float* __restrict__ wgt,
    const float* __restrict__ quat, const float* __restrict__ base_t,
    const float* __restrict__ jstate, const float* __restrict__ W_loc,
    const float* __restrict__ W_axis, float* __restrict__ out,
    float* __restrict__ partials) {
  __shared__ float sb[BDIM];
  __shared__ float Ts[16];
  __shared__ float part[128 * 3];
  __shared__ float red[4];

  const int tid = threadIdx.x;
  const int bid = blockIdx.x;
  const int pid = bid >> 8;  // part id (256 blocks per part)

  if (tid < BDIM) sb[tid] = beta[tid];

  if (tid < 64) {
    // --- base transform (all lanes of wave 0, redundantly: cheap) ---
    float q0 = quat[0], q1 = quat[1], q2 = quat[2], q3 = quat[3];
    float qn = sqrtf(q0 * q0 + q1 * q1 + q2 * q2 + q3 * q3);
    float a = q0 / qn, b = q1 / qn, c = q2 / qn, d = q3 / qn;
    float R00 = 1.f - 2.f * c * c - 2.f * d * d, R01 = 2.f * b * c - 2.f * a * d,
          R02 = 2.f * a * c + 2.f * b * d;
    float R10 = 2.f * b * c + 2.f * a * d, R11 = 1.f - 2.f * b * b - 2.f * d * d,
          R12 = 2.f * c * d - 2.f * a * b;
    float R20 = 2.f * b * d - 2.f * a * c, R21 = 2.f * a * b + 2.f * c * d,
          R22 = 1.f - 2.f * b * b - 2.f * c * c;
    float t0 = base_t[0], t1 = base_t[1], t2 = base_t[2];
    float T[16] = {R00, R01, R02, t0, R10, R11, R12, t1,
                   R20, R21, R22, t2, 0.f, 0.f, 0.f, 1.f};

    const bool write_small = (bid >= 1 && bid <= NJ);  // blocks 1..7 (pid==0)
    const bool need_joint = (pid > 0) || write_small;

    if (need_joint) {
      const int j = (pid > 0) ? (pid - 1) : (bid - 1);
      float be = beta[tid];
      float l0 = be * W_loc[tid * 21 + j * 3 + 0];
      float l1 = be * W_loc[tid * 21 + j * 3 + 1];
      float l2 = be * W_loc[tid * 21 + j * 3 + 2];
      float x0 = be * W_axis[tid * 21 + j * 3 + 0];
      float x1 = be * W_axis[tid * 21 + j * 3 + 1];
      float x2 = be * W_axis[tid * 21 + j * 3 + 2];
#pragma unroll
      for (int off = 32; off > 0; off >>= 1) {
        l0 += __shfl_xor(l0, off, 64);
        l1 += __shfl_xor(l1, off, 64);
        l2 += __shfl_xor(l2, off, 64);
        x0 += __shfl_xor(x0, off, 64);
        x1 += __shfl_xor(x1, off, 64);
        x2 += __shfl_xor(x2, off, 64);
      }
      float xn = sqrtf(x0 * x0 + x1 * x1 + x2 * x2);
      x0 /= xn; x1 /= xn; x2 /= xn;
      float aa = R00 * l0 + R01 * l1 + R02 * l2 + t0;
      float bb = R10 * l0 + R11 * l1 + R12 * l2 + t1;
      float cc = R20 * l0 + R21 * l1 + R22 * l2 + t2;
      float u = R00 * x0 + R01 * x1 + R02 * x2;
      float v = R10 * x0 + R11 * x1 + R12 * x2;
      float w = R20 * x0 + R21 * x1 + R22 * x2;
      float th = jstate[j];
      float cth = cosf(-th), sth = sinf(-th), omc = 1.f - cth;
      float rel[12];
      rel[0]  = u * u + (v * v + w * w) * cth;
      rel[1]  = u * v * omc - w * sth;
      rel[2]  = u * w * omc + v * sth;
      rel[3]  = (aa * (v * v + w * w) - u * (bb * v + cc * w)) * omc + (bb * w - cc * v) * sth;
      rel[4]  = u * v * omc + w * sth;
      rel[5]  = v * v + (u * u + w * w) * cth;
      rel[6]  = v * w * omc - u * sth;
      rel[7]  = (bb * (u * u + w * w) - v * (aa * u + cc * w)) * omc + (cc * u - aa * w) * sth;
      rel[8]  = u * w * omc - v * sth;
      rel[9]  = v * w * omc + u * sth;
      rel[10] = w * w + (u * u + v * v) * cth;
      rel[11] = (cc * (u * u + v * v) - w * (aa * u + bb * v)) * omc + (aa * v - bb * u) * sth;
      float C[12];
#pragma unroll
      for (int r = 0; r < 3; r++)
#pragma unroll
        for (int cx = 0; cx < 4; cx++)
          C[r * 4 + cx] = rel[r * 4 + 0] * T[0 + cx] + rel[r * 4 + 1] * T[4 + cx] +
                          rel[r * 4 + 2] * T[8 + cx] + rel[r * 4 + 3] * T[12 + cx];
      if (tid == 0) {
        if (pid > 0) {
          for (int i = 0; i < 12; i++) Ts[i] = C[i];
          Ts[12] = 0.f; Ts[13] = 0.f; Ts[14] = 0.f; Ts[15] = 1.f;
        } else {
          for (int i = 0; i < 16; i++) Ts[i] = T[i];
        }
        if (write_small) {
          out[OFF_JLOC + j * 3 + 0] = l0;
          out[OFF_JLOC + j * 3 + 1] = l1;
          out[OFF_JLOC + j * 3 + 2] = l2;
          out[OFF_JAXIS + j * 3 + 0] = x0;
          out[OFF_JAXIS + j * 3 + 1] = x1;
          out[OFF_JAXIS + j * 3 + 2] = x2;
          out[OFF_NANCH + j * 3 + 0] = aa;
          out[OFF_NANCH + j * 3 + 1] = bb;
          out[OFF_NANCH + j * 3 + 2] = cc;
          out[OFF_NAXIS + j * 3 + 0] = u;
          out[OFF_NAXIS + j * 3 + 1] = v;
          out[OFF_NAXIS + j * 3 + 2] = w;
          for (int i = 0; i < 12; i++) out[OFF_REL + j * 16 + i] = rel[i];
          out[OFF_REL + j * 16 + 12] = 0.f;
          out[OFF_REL + j * 16 + 13] = 0.f;
          out[OFF_REL + j * 16 + 14] = 0.f;
          out[OFF_REL + j * 16 + 15] = 1.f;
        }
      }
    } else if (tid == 0) {
      for (int i = 0; i < 16; i++) Ts[i] = T[i];
      if (bid == 0)
        for (int i = 0; i < 16; i++) out[OFF_BASET + i] = T[i];
    }
  }
  __syncthreads();

  // --- main einsum + objective ---
  const int idx = tid & 127;  // point-within-block
  const int h = tid >> 7;     // e-half (wave-uniform)
  const int p = bid * 128 + idx;

  const float* base = W_kp + (size_t)(h * 32) * WSTRIDE + (size_t)p * 3;
  float ax = 0.f, ay = 0.f, az = 0.f;
#pragma unroll 8
  for (int e = 0; e < 32; e++) {
    float3 vv = *(const float3*)(base + (size_t)e * WSTRIDE);
    float be = sb[h * 32 + e];
    ax = fmaf(be, vv.x, ax);
    ay = fmaf(be, vv.y, ay);
    az = fmaf(be, vv.z, az);
  }

  if (h == 1) {
    part[idx * 3 + 0] = ax;
    part[idx * 3 + 1] = ay;
    part[idx * 3 + 2] = az;
  }
  __syncthreads();

  float vsum = 0.f;
  if (h == 0) {
    float x = ax + part[idx * 3 + 0];
    float y = ay + part[idx * 3 + 1];
    float z = az + part[idx * 3 + 2];
    float3 o; o.x = x; o.y = y; o.z = z;
    *(float3*)(out + OFF_NKPOUT + (size_t)p * 3) = o;

    float3 pk = *(const float3*)(pred_kp + (size_t)p * 3);
    float w = wgt[p];
    float dx = Ts[0] * x + Ts[1] * y + Ts[2]  * z + Ts[3]  - pk.x;
    float dy = Ts[4] * x + Ts[5] * y + Ts[6]  * z + Ts[7]  - pk.y;
    float dz = Ts[8] * x + Ts[9] * y + Ts[10] * z + Ts[11] - pk.z;
    vsum = sqrtf(dx * dx + dy * dy + dz * dz) * w;
  }
#pragma unroll
  for (int off = 32; off > 0; off >>= 1) vsum += __shfl_down(vsum, off, 64);
  if ((tid & 63) == 0) red[tid >> 6] = vsum;
  __syncthreads();
  if (tid == 0) partials[bid] = red[0] + red[1] + red[2] + red[3];
}

// ---------------------------------------------------------------------------
// Kernel 2 (finish): 1 block x 256. Deterministic reduce of 2048 partials +
// beta regularizer -> out[0]. Fixed reduction tree, same every call.
// ---------------------------------------------------------------------------
__global__ __launch_bounds__(256) void finish_kernel(
    const float* __restrict__ partials, const float* __restrict__ beta,
    float* __restrict__ out_obj) {
  __shared__ float red[4];
  int tid = threadIdx.x;
  float s = 0.f;
#pragma unroll
  for (int k = 0; k < NBLK / 256; k++) s += partials[tid + 256 * k];
#pragma unroll
  for (int off = 32; off > 0; off >>= 1) s += __shfl_down(s, off, 64);
  if ((tid & 63) == 0) red[tid >> 6] = s;
  __syncthreads();
  if (tid == 0) {
    float reg = 0.f;
    for (int e = 0; e < BDIM; e++) {
      float be = beta[e];
      reg += be * be;
    }
    out_obj[0] = (red[0] + red[1] + red[2] + red[3]) * (1.0f / (float)NPTS) +
                 (reg / (float)BDIM) * 0.001f;
  }
}

extern "C" void kernel_launch(void* const* d_in, const int* in_sizes, int n_in,
                              void* d_out, int out_size, void* d_ws, size_t ws_size,
                              hipStream_t stream) {
  const float* pred_kp = (const float*)d_in[0];
  const float* quat    = (const float*)d_in[1];
  const float* base_t  = (const float*)d_in[2];
  const float* jstate  = (const float*)d_in[3];
  const float* beta    = (const float*)d_in[4];
  const float* wgt     = (const float*)d_in[5];
  const float* W_kp    = (const float*)d_in[6];
  const float* W_loc   = (const float*)d_in[7];
  const float* W_axis  = (const float*)d_in[8];
  float* out      = (float*)d_out;
  float* partials = (float*)d_ws;

  fused_all<<<NBLK, 256, 0, stream>>>(W_kp, beta, pred_kp, wgt, quat, base_t,
                                      jstate, W_loc, W_axis, out, partials);
  finish_kernel<<<1, 256, 0, stream>>>(partials, beta, out);
}